// Round 1
// baseline (1431.288 us; speedup 1.0000x reference)
//
#include <hip/hip_runtime.h>

#define DI __device__ __forceinline__

DI float4 fmax4(float4 a, float4 b){
  return make_float4(fmaxf(a.x,b.x),fmaxf(a.y,b.y),fmaxf(a.z,b.z),fmaxf(a.w,b.w));
}

DI float wred(float v){
  #pragma unroll
  for (int o = 32; o > 0; o >>= 1) v += __shfl_xor(v, o, 64);
  return v;
}

// ---------------------------------------------------------------------------
// Fused channel-max over (B,512,P) for grd (P=256), sat (P=256), pts (P=1024).
// One f4 output per 64-lane slot; 4-way split over the 512 channels via waves.
// ---------------------------------------------------------------------------
__global__ __launch_bounds__(256) void k_masks(const float* __restrict__ g,
    const float* __restrict__ p, const float* __restrict__ s,
    float* __restrict__ mg, float* __restrict__ mp, float* __restrict__ ms){
  __shared__ float4 lds[256];
  int t = threadIdx.x;
  int o = blockIdx.x * 64 + (t & 63);
  int ck = t >> 6;
  const float* src; float* dst; int b, p4, P4;
  if (o < 8192)       { b = o >> 6;            p4 = o & 63;          src = g; dst = mg; P4 = 64;  }
  else if (o < 16384) { int q = o - 8192;  b = q >> 6;  p4 = q & 63;  src = s; dst = ms; P4 = 64;  }
  else                { int q = o - 16384; b = q >> 8;  p4 = q & 255; src = p; dst = mp; P4 = 256; }
  const float4* a = (const float4*)src + ((size_t)b*512 + (size_t)ck*128) * P4 + p4;
  float4 v0 = make_float4(-1e30f,-1e30f,-1e30f,-1e30f), v1 = v0, v2 = v0, v3 = v0;
  for (int cc = 0; cc < 128; cc += 4){
    v0 = fmax4(v0, a[0]);
    v1 = fmax4(v1, a[(size_t)P4]);
    v2 = fmax4(v2, a[(size_t)2*P4]);
    v3 = fmax4(v3, a[(size_t)3*P4]);
    a += (size_t)4*P4;
  }
  v0 = fmax4(fmax4(v0,v1), fmax4(v2,v3));
  lds[t] = v0;
  __syncthreads();
  if (t < 64){
    float4 r = fmax4(fmax4(lds[t], lds[t+64]), fmax4(lds[t+128], lds[t+192]));
    ((float4*)dst)[(size_t)b*P4 + p4] = r;
  }
}

// ---------------------------------------------------------------------------
// SA stage 1: m[b,j,d] = sum_i mask[b,i] * w1[i,j,d] + b1[j,d]
// grid = (J8/1024) * (B/4); thread covers 4 consecutive jd, 4 batches.
// ---------------------------------------------------------------------------
__global__ __launch_bounds__(256) void k_sa1(const float* __restrict__ mask,
    const float* __restrict__ w1, const float* __restrict__ b1,
    float* __restrict__ m, int I, int J8){
  int t = threadIdx.x;
  int jdb = blockIdx.x >> 5, bt = blockIdx.x & 31;
  int jd = jdb*1024 + t*4;
  int b0 = bt*4;
  float4 bias = *(const float4*)(b1 + jd);
  float4 acc[4];
  #pragma unroll
  for (int bb = 0; bb < 4; bb++) acc[bb] = bias;
  for (int i = 0; i < I; i++){
    float4 w = *(const float4*)(w1 + (size_t)i*J8 + jd);
    #pragma unroll
    for (int bb = 0; bb < 4; bb++){
      float mv = mask[(size_t)(b0+bb)*I + i];
      acc[bb].x += mv*w.x; acc[bb].y += mv*w.y; acc[bb].z += mv*w.z; acc[bb].w += mv*w.w;
    }
  }
  #pragma unroll
  for (int bb = 0; bb < 4; bb++)
    *(float4*)(m + (size_t)(b0+bb)*J8 + jd) = acc[bb];
}

// ---------------------------------------------------------------------------
// SA stage 2: w[b,i,d] = sum_j m[b,j,d] * w2[j,i,d] + b2[i,d]
// ---------------------------------------------------------------------------
__global__ __launch_bounds__(256) void k_sa2(const float* __restrict__ m,
    const float* __restrict__ w2, const float* __restrict__ b2,
    float* __restrict__ w, int J, int I8, int J8){
  int t = threadIdx.x;
  int idb = blockIdx.x >> 5, bt = blockIdx.x & 31;
  int id = idb*1024 + t*4;
  int quad = id & 4;      // d-range base: 0 or 4
  int b0 = bt*4;
  float4 bias = *(const float4*)(b2 + id);
  float4 acc[4];
  #pragma unroll
  for (int bb = 0; bb < 4; bb++) acc[bb] = bias;
  for (int j = 0; j < J; j++){
    float4 wv = *(const float4*)(w2 + (size_t)j*I8 + id);
    #pragma unroll
    for (int bb = 0; bb < 4; bb++){
      float4 mv = *(const float4*)(m + (size_t)(b0+bb)*J8 + j*8 + quad);
      acc[bb].x += mv.x*wv.x; acc[bb].y += mv.y*wv.y;
      acc[bb].z += mv.z*wv.z; acc[bb].w += mv.w*wv.w;
    }
  }
  #pragma unroll
  for (int bb = 0; bb < 4; bb++)
    *(float4*)(w + (size_t)(b0+bb)*I8 + id) = acc[bb];
}

// ---------------------------------------------------------------------------
// out[b,c,d] = sum_k A[b,c,k] * W[b,k,d]  (c in 512, d in 8), + sumsq per b.
// grid = B*4 (128-row tiles). W[b] staged in LDS (broadcast reads).
// Thread: 2 rows x 8 d, K split 4 ways across waves, LDS-pad-17 reduce.
// ---------------------------------------------------------------------------
__global__ __launch_bounds__(256) void k_gemm(const float* __restrict__ A,
    const float* __restrict__ W, float* __restrict__ out,
    float* __restrict__ ssq, int K){
  __shared__ float wl[8192];
  __shared__ float red[256*17];
  int t = threadIdx.x;
  int b = blockIdx.x >> 2, ct = blockIdx.x & 3;
  int K8 = K*8;
  for (int idx = t*4; idx < K8; idx += 1024)
    *(float4*)(wl + idx) = *(const float4*)(W + (size_t)b*K8 + idx);
  __syncthreads();
  int r = t & 63, kh = t >> 6;
  int Ks = K >> 2;
  const float* a0 = A + ((size_t)b*512 + ct*128 + r*2) * K + kh*Ks;
  float acc[16];
  #pragma unroll
  for (int i = 0; i < 16; i++) acc[i] = 0.f;
  for (int kk = 0; kk < Ks; kk += 4){
    float4 x0 = *(const float4*)(a0 + kk);
    float4 x1 = *(const float4*)(a0 + K + kk);
    const float* wp = wl + (kh*Ks + kk)*8;
    float xs0[4] = {x0.x, x0.y, x0.z, x0.w};
    float xs1[4] = {x1.x, x1.y, x1.z, x1.w};
    #pragma unroll
    for (int mm = 0; mm < 4; mm++){
      #pragma unroll
      for (int d = 0; d < 8; d++){
        float wv = wp[mm*8 + d];
        acc[d]     += xs0[mm]*wv;
        acc[8 + d] += xs1[mm]*wv;
      }
    }
  }
  float* rp = red + t*17;
  #pragma unroll
  for (int i = 0; i < 16; i++) rp[i] = acc[i];
  __syncthreads();
  if (t < 64){
    float v[16];
    #pragma unroll
    for (int i = 0; i < 16; i++)
      v[i] = red[t*17 + i] + red[(t+64)*17 + i] + red[(t+128)*17 + i] + red[(t+192)*17 + i];
    float* op = out + ((size_t)b*512 + ct*128 + t*2) * 8;
    #pragma unroll
    for (int i = 0; i < 16; i += 4)
      *(float4*)(op + i) = make_float4(v[i], v[i+1], v[i+2], v[i+3]);
    float s = 0.f;
    #pragma unroll
    for (int i = 0; i < 16; i++) s += v[i]*v[i];
    s = wred(s);
    if (t == 0) atomicAdd(ssq + b, s);
  }
}

// ---------------------------------------------------------------------------
// Per-patch (8192): sat SA inline, patch GEMM (512x4 @ 4x8), L2 norm,
// dots vs normalized grd/pts descriptors, write cost_map row + ms.
// ---------------------------------------------------------------------------
#define OUT2_OFF 33562624
__global__ __launch_bounds__(256) void k_sat(const float* __restrict__ sat,
    const float* __restrict__ msat,
    const float* __restrict__ w1, const float* __restrict__ b1,
    const float* __restrict__ w2, const float* __restrict__ b2,
    const float* __restrict__ gun, const float* __restrict__ pun,
    const float* __restrict__ ssg, const float* __restrict__ ssp,
    float* __restrict__ out){
  __shared__ float ml[16];
  __shared__ float wl[32];
  __shared__ float rl[4][3];
  __shared__ float bcast[1];
  int t = threadIdx.x;
  int patch = blockIdx.x;
  int b = patch >> 6, s1 = (patch >> 3) & 7, s2 = patch & 7;
  int sbase = s1*32 + s2*2;
  if (t < 16){
    int j = t >> 3, d = t & 7;
    float acc = b1[j*8 + d];
    #pragma unroll
    for (int k = 0; k < 4; k++){
      float mk = msat[(size_t)b*256 + sbase + (k>>1)*16 + (k&1)];
      acc += mk * w1[k*16 + j*8 + d];
    }
    ml[t] = acc;
  }
  __syncthreads();
  if (t < 32){
    int i = t >> 3, d = t & 7;
    float acc = b2[i*8 + d];
    acc += ml[d]*w2[i*8 + d] + ml[8 + d]*w2[32 + i*8 + d];
    wl[t] = acc;
  }
  __syncthreads();
  float wr[4][8];
  #pragma unroll
  for (int k = 0; k < 4; k++)
    #pragma unroll
    for (int d = 0; d < 8; d++) wr[k][d] = wl[k*8 + d];
  const float* ap = sat + ((size_t)b*512 + 2*t) * 256 + sbase;
  float pg[16];
  #pragma unroll
  for (int cc = 0; cc < 2; cc++){
    const float* a = ap + cc*256;
    float a0 = a[0], a1 = a[1], a2 = a[16], a3 = a[17];
    #pragma unroll
    for (int d = 0; d < 8; d++)
      pg[cc*8 + d] = a0*wr[0][d] + a1*wr[1][d] + a2*wr[2][d] + a3*wr[3][d];
  }
  const float* g = gun + (size_t)b*4096 + t*16;
  const float* p = pun + (size_t)b*4096 + t*16;
  float ss = 0.f, dg = 0.f, dp = 0.f;
  #pragma unroll
  for (int i = 0; i < 16; i++){
    ss += pg[i]*pg[i];
    dg += pg[i]*g[i];
    dp += pg[i]*p[i];
  }
  ss = wred(ss); dg = wred(dg); dp = wred(dp);
  int wv = t >> 6;
  if ((t & 63) == 0){ rl[wv][0] = ss; rl[wv][1] = dg; rl[wv][2] = dp; }
  __syncthreads();
  if (t == 0){
    float sst = rl[0][0] + rl[1][0] + rl[2][0] + rl[3][0];
    float dgt = rl[0][1] + rl[1][1] + rl[2][1] + rl[3][1];
    float dpt = rl[0][2] + rl[1][2] + rl[2][2] + rl[3][2];
    float satn = fmaxf(sqrtf(sst), 1e-12f);
    float inv = 1.f / satn;
    float gn = fmaxf(sqrtf(ssg[b]), 1e-12f);
    float pn = fmaxf(sqrtf(ssp[b]), 1e-12f);
    float msv = dgt*inv/gn + dpt*inv/pn;
    bcast[0] = inv;
    out[(size_t)patch*4097] = msv;
    out[OUT2_OFF + (size_t)patch] = msv;
  }
  __syncthreads();
  float inv = bcast[0];
  float* op = out + (size_t)patch*4097 + 1 + t*16;
  #pragma unroll
  for (int i = 0; i < 16; i++) op[i] = pg[i]*inv;
}

extern "C" void kernel_launch(void* const* d_in, const int* in_sizes, int n_in,
                              void* d_out, int out_size, void* d_ws, size_t ws_size,
                              hipStream_t stream){
  const float* grd  = (const float*)d_in[0];
  const float* pts  = (const float*)d_in[1];
  const float* satl = (const float*)d_in[2];
  const float* gw1  = (const float*)d_in[3];
  const float* gb1  = (const float*)d_in[4];
  const float* gw2  = (const float*)d_in[5];
  const float* gb2  = (const float*)d_in[6];
  const float* sw1  = (const float*)d_in[7];
  const float* sb1  = (const float*)d_in[8];
  const float* sw2  = (const float*)d_in[9];
  const float* sb2  = (const float*)d_in[10];
  const float* pw1  = (const float*)d_in[11];
  const float* pb1  = (const float*)d_in[12];
  const float* pw2  = (const float*)d_in[13];
  const float* pb2  = (const float*)d_in[14];
  float* out = (float*)d_out;
  float* W = (float*)d_ws;
  float* mg   = W + 0;        // (128,256)
  float* msat = W + 32768;    // (128,256)
  float* mp   = W + 65536;    // (128,1024)
  float* mgrd = W + 196608;   // (128,128,8)
  float* wgrd = W + 327680;   // (128,256,8)
  float* mpc  = W + 589824;   // (128,512,8)
  float* wpc  = W + 1114112;  // (128,1024,8)
  float* gun  = W + 2162688;  // (128,4096)
  float* pun  = W + 2686976;  // (128,4096)
  float* ssg  = W + 3211264;  // (128)
  float* ssp  = W + 3211392;  // (128)

  hipMemsetAsync(ssg, 0, 256*sizeof(float), stream);
  k_masks<<<768, 256, 0, stream>>>(grd, pts, satl, mg, mp, msat);
  k_sa1<<<32,  256, 0, stream>>>(mg, gw1, gb1, mgrd, 256, 1024);
  k_sa1<<<128, 256, 0, stream>>>(mp, pw1, pb1, mpc, 1024, 4096);
  k_sa2<<<64,  256, 0, stream>>>(mgrd, gw2, gb2, wgrd, 128, 2048, 1024);
  k_sa2<<<256, 256, 0, stream>>>(mpc, pw2, pb2, wpc, 512, 8192, 4096);
  k_gemm<<<512, 256, 0, stream>>>(grd, wgrd, gun, ssg, 256);
  k_gemm<<<512, 256, 0, stream>>>(pts, wpc, pun, ssp, 1024);
  k_sat<<<8192, 256, 0, stream>>>(satl, msat, sw1, sb1, sw2, sb2,
                                  gun, pun, ssg, ssp, out);
}

// Round 4
// 856.520 us; speedup vs baseline: 1.6711x; 1.6711x over previous
//
#include <hip/hip_runtime.h>

#define DI __device__ __forceinline__

DI float4 fmax4(float4 a, float4 b){
  return make_float4(fmaxf(a.x,b.x),fmaxf(a.y,b.y),fmaxf(a.z,b.z),fmaxf(a.w,b.w));
}

DI float wred(float v){
  #pragma unroll
  for (int o = 32; o > 0; o >>= 1) v += __shfl_xor(v, o, 64);
  return v;
}

DI void facc(float4& a, float s, float4 w){
  a.x += s*w.x; a.y += s*w.y; a.z += s*w.z; a.w += s*w.w;
}

// ---------------------------------------------------------------------------
// Fused channel-max over (B,512,P) for grd (P=256), sat (P=256), pts (P=1024).
// ---------------------------------------------------------------------------
__global__ __launch_bounds__(256) void k_masks(const float* __restrict__ g,
    const float* __restrict__ p, const float* __restrict__ s,
    float* __restrict__ mg, float* __restrict__ mp, float* __restrict__ ms){
  __shared__ float4 lds[256];
  int t = threadIdx.x;
  int o = blockIdx.x * 64 + (t & 63);
  int ck = t >> 6;
  const float* src; float* dst; int b, p4, P4;
  if (o < 8192)       { b = o >> 6;            p4 = o & 63;          src = g; dst = mg; P4 = 64;  }
  else if (o < 16384) { int q = o - 8192;  b = q >> 6;  p4 = q & 63;  src = s; dst = ms; P4 = 64;  }
  else                { int q = o - 16384; b = q >> 8;  p4 = q & 255; src = p; dst = mp; P4 = 256; }
  const float4* a = (const float4*)src + ((size_t)b*512 + (size_t)ck*128) * P4 + p4;
  float4 v0 = make_float4(-1e30f,-1e30f,-1e30f,-1e30f), v1 = v0, v2 = v0, v3 = v0;
  for (int cc = 0; cc < 128; cc += 4){
    v0 = fmax4(v0, a[0]);
    v1 = fmax4(v1, a[(size_t)P4]);
    v2 = fmax4(v2, a[(size_t)2*P4]);
    v3 = fmax4(v3, a[(size_t)3*P4]);
    a += (size_t)4*P4;
  }
  v0 = fmax4(fmax4(v0,v1), fmax4(v2,v3));
  lds[t] = v0;
  __syncthreads();
  if (t < 64){
    float4 r = fmax4(fmax4(lds[t], lds[t+64]), fmax4(lds[t+128], lds[t+192]));
    ((float4*)dst)[(size_t)b*P4 + p4] = r;
  }
}

// ---------------------------------------------------------------------------
// SA stage 1: m[b,jd] = sum_i mask[b,i] * w1[i,jd] + b1[jd]
// Block: 256 cols (64 f4) x 8 batches, K split 4-way across wave groups.
// grid = (J8/256, B/8). Mask reads are wave-uniform (L1 broadcast).
// ---------------------------------------------------------------------------
__global__ __launch_bounds__(256) void k_sa1(const float* __restrict__ mask,
    const float* __restrict__ w1, const float* __restrict__ b1,
    float* __restrict__ m, int I, int J8){
  __shared__ float4 red[2048];
  int t = threadIdx.x;
  int tx = t & 63, tg = t >> 6;
  int jd = blockIdx.x*256 + tx*4;
  int b0 = blockIdx.y*8;
  int KC = I >> 2;
  int k0 = tg*KC;
  float4 acc[8];
  #pragma unroll
  for (int u = 0; u < 8; u++) acc[u] = make_float4(0,0,0,0);
  const float* w1p = w1 + (size_t)k0*J8 + jd;
  for (int kk = 0; kk < KC; kk += 4){
    float mv[8][4];
    #pragma unroll
    for (int u = 0; u < 8; u++){
      float4 q = *(const float4*)(mask + (size_t)(b0+u)*I + k0 + kk);
      mv[u][0]=q.x; mv[u][1]=q.y; mv[u][2]=q.z; mv[u][3]=q.w;
    }
    #pragma unroll
    for (int s = 0; s < 4; s++){
      float4 w = *(const float4*)(w1p + (size_t)s*J8);
      #pragma unroll
      for (int u = 0; u < 8; u++) facc(acc[u], mv[u][s], w);
    }
    w1p += (size_t)4*J8;
  }
  #pragma unroll
  for (int u = 0; u < 8; u++) red[(tg*64+tx)*8 + (u ^ (tx&7))] = acc[u];
  __syncthreads();
  #pragma unroll
  for (int e = 0; e < 2; e++){
    int oi = t*2 + e;
    int ox = oi >> 3, ob = oi & 7;
    float4 s = make_float4(0,0,0,0);
    #pragma unroll
    for (int g = 0; g < 4; g++){
      float4 v = red[(g*64+ox)*8 + (ob ^ (ox&7))];
      s.x+=v.x; s.y+=v.y; s.z+=v.z; s.w+=v.w;
    }
    int jd2 = blockIdx.x*256 + ox*4;
    float4 bv = *(const float4*)(b1 + jd2);
    s.x+=bv.x; s.y+=bv.y; s.z+=bv.z; s.w+=bv.w;
    *(float4*)(m + (size_t)(b0+ob)*J8 + jd2) = s;
  }
}

// ---------------------------------------------------------------------------
// SA stage 2: w[b,id] = sum_j m[b,j*8+d] * w2[j,id] + b2[id]   (d = id&7)
// Same block structure; m reads broadcast from L1/L2.
// ---------------------------------------------------------------------------
__global__ __launch_bounds__(256) void k_sa2(const float* __restrict__ m,
    const float* __restrict__ w2, const float* __restrict__ b2,
    float* __restrict__ w, int J, int I8, int J8m){
  __shared__ float4 red[2048];
  int t = threadIdx.x;
  int tx = t & 63, tg = t >> 6;
  int id = blockIdx.x*256 + tx*4;
  int quad = id & 4;
  int b0 = blockIdx.y*8;
  int KC = J >> 2;
  int j0 = tg*KC;
  float4 acc[8];
  #pragma unroll
  for (int u = 0; u < 8; u++) acc[u] = make_float4(0,0,0,0);
  const float* w2p = w2 + (size_t)j0*I8 + id;
  for (int j = 0; j < KC; j++){
    float4 wv = *(const float4*)w2p; w2p += I8;
    #pragma unroll
    for (int u = 0; u < 8; u++){
      float4 mv = *(const float4*)(m + (size_t)(b0+u)*J8m + (size_t)(j0+j)*8 + quad);
      acc[u].x += mv.x*wv.x; acc[u].y += mv.y*wv.y;
      acc[u].z += mv.z*wv.z; acc[u].w += mv.w*wv.w;
    }
  }
  #pragma unroll
  for (int u = 0; u < 8; u++) red[(tg*64+tx)*8 + (u ^ (tx&7))] = acc[u];
  __syncthreads();
  #pragma unroll
  for (int e = 0; e < 2; e++){
    int oi = t*2 + e;
    int ox = oi >> 3, ob = oi & 7;
    float4 s = make_float4(0,0,0,0);
    #pragma unroll
    for (int g = 0; g < 4; g++){
      float4 v = red[(g*64+ox)*8 + (ob ^ (ox&7))];
      s.x+=v.x; s.y+=v.y; s.z+=v.z; s.w+=v.w;
    }
    int id2 = blockIdx.x*256 + ox*4;
    float4 bv = *(const float4*)(b2 + id2);
    s.x+=bv.x; s.y+=bv.y; s.z+=bv.z; s.w+=bv.w;
    *(float4*)(w + (size_t)(b0+ob)*I8 + id2) = s;
  }
}

// ---------------------------------------------------------------------------
// out[b,c,d] = sum_k A[b,c,k] * W[b,k,d]  (c in 512, d in 8), + sumsq per b.
// ---------------------------------------------------------------------------
__global__ __launch_bounds__(256) void k_gemm(const float* __restrict__ A,
    const float* __restrict__ W, float* __restrict__ out,
    float* __restrict__ ssq, int K){
  __shared__ float wl[8192];
  __shared__ float red[256*17];
  int t = threadIdx.x;
  int b = blockIdx.x >> 2, ct = blockIdx.x & 3;
  int K8 = K*8;
  for (int idx = t*4; idx < K8; idx += 1024)
    *(float4*)(wl + idx) = *(const float4*)(W + (size_t)b*K8 + idx);
  __syncthreads();
  int r = t & 63, kh = t >> 6;
  int Ks = K >> 2;
  const float* a0 = A + ((size_t)b*512 + ct*128 + r*2) * K + kh*Ks;
  float acc[16];
  #pragma unroll
  for (int i = 0; i < 16; i++) acc[i] = 0.f;
  for (int kk = 0; kk < Ks; kk += 4){
    float4 x0 = *(const float4*)(a0 + kk);
    float4 x1 = *(const float4*)(a0 + K + kk);
    const float* wp = wl + (kh*Ks + kk)*8;
    float xs0[4] = {x0.x, x0.y, x0.z, x0.w};
    float xs1[4] = {x1.x, x1.y, x1.z, x1.w};
    #pragma unroll
    for (int mm = 0; mm < 4; mm++){
      #pragma unroll
      for (int d = 0; d < 8; d++){
        float wv = wp[mm*8 + d];
        acc[d]     += xs0[mm]*wv;
        acc[8 + d] += xs1[mm]*wv;
      }
    }
  }
  float* rp = red + t*17;
  #pragma unroll
  for (int i = 0; i < 16; i++) rp[i] = acc[i];
  __syncthreads();
  if (t < 64){
    float v[16];
    #pragma unroll
    for (int i = 0; i < 16; i++)
      v[i] = red[t*17 + i] + red[(t+64)*17 + i] + red[(t+128)*17 + i] + red[(t+192)*17 + i];
    float* op = out + ((size_t)b*512 + ct*128 + t*2) * 8;
    #pragma unroll
    for (int i = 0; i < 16; i += 4)
      *(float4*)(op + i) = make_float4(v[i], v[i+1], v[i+2], v[i+3]);
    float s = 0.f;
    #pragma unroll
    for (int i = 0; i < 16; i++) s += v[i]*v[i];
    s = wred(s);
    if (t == 0) atomicAdd(ssq + b, s);
  }
}

// ---------------------------------------------------------------------------
// Per-patch (8192): sat SA inline, patch GEMM (512x4 @ 4x8), L2 norm,
// dots vs normalized grd/pts descriptors, write cost_map row + ms.
// ---------------------------------------------------------------------------
#define OUT2_OFF 33562624
__global__ __launch_bounds__(256) void k_sat(const float* __restrict__ sat,
    const float* __restrict__ msat,
    const float* __restrict__ w1, const float* __restrict__ b1,
    const float* __restrict__ w2, const float* __restrict__ b2,
    const float* __restrict__ gun, const float* __restrict__ pun,
    const float* __restrict__ ssg, const float* __restrict__ ssp,
    float* __restrict__ out){
  __shared__ float ml[16];
  __shared__ float wl[32];
  __shared__ float rl[4][3];
  __shared__ float bcast[1];
  int t = threadIdx.x;
  int patch = blockIdx.x;
  int b = patch >> 6, s1 = (patch >> 3) & 7, s2 = patch & 7;
  int sbase = s1*32 + s2*2;
  if (t < 16){
    int j = t >> 3, d = t & 7;
    float acc = b1[j*8 + d];
    #pragma unroll
    for (int k = 0; k < 4; k++){
      float mk = msat[(size_t)b*256 + sbase + (k>>1)*16 + (k&1)];
      acc += mk * w1[k*16 + j*8 + d];
    }
    ml[t] = acc;
  }
  __syncthreads();
  if (t < 32){
    int i = t >> 3, d = t & 7;
    float acc = b2[i*8 + d];
    acc += ml[d]*w2[i*8 + d] + ml[8 + d]*w2[32 + i*8 + d];
    wl[t] = acc;
  }
  __syncthreads();
  float wr[4][8];
  #pragma unroll
  for (int k = 0; k < 4; k++)
    #pragma unroll
    for (int d = 0; d < 8; d++) wr[k][d] = wl[k*8 + d];
  const float* ap = sat + ((size_t)b*512 + 2*t) * 256 + sbase;
  float pg[16];
  #pragma unroll
  for (int cc = 0; cc < 2; cc++){
    const float* a = ap + cc*256;
    float a0 = a[0], a1 = a[1], a2 = a[16], a3 = a[17];
    #pragma unroll
    for (int d = 0; d < 8; d++)
      pg[cc*8 + d] = a0*wr[0][d] + a1*wr[1][d] + a2*wr[2][d] + a3*wr[3][d];
  }
  const float* g = gun + (size_t)b*4096 + t*16;
  const float* p = pun + (size_t)b*4096 + t*16;
  float ss = 0.f, dg = 0.f, dp = 0.f;
  #pragma unroll
  for (int i = 0; i < 16; i++){
    ss += pg[i]*pg[i];
    dg += pg[i]*g[i];
    dp += pg[i]*p[i];
  }
  ss = wred(ss); dg = wred(dg); dp = wred(dp);
  int wv = t >> 6;
  if ((t & 63) == 0){ rl[wv][0] = ss; rl[wv][1] = dg; rl[wv][2] = dp; }
  __syncthreads();
  if (t == 0){
    float sst = rl[0][0] + rl[1][0] + rl[2][0] + rl[3][0];
    float dgt = rl[0][1] + rl[1][1] + rl[2][1] + rl[3][1];
    float dpt = rl[0][2] + rl[1][2] + rl[2][2] + rl[3][2];
    float satn = fmaxf(sqrtf(sst), 1e-12f);
    float inv = 1.f / satn;
    float gn = fmaxf(sqrtf(ssg[b]), 1e-12f);
    float pn = fmaxf(sqrtf(ssp[b]), 1e-12f);
    float msv = dgt*inv/gn + dpt*inv/pn;
    bcast[0] = inv;
    out[(size_t)patch*4097] = msv;
    out[OUT2_OFF + (size_t)patch] = msv;
  }
  __syncthreads();
  float inv = bcast[0];
  float* op = out + (size_t)patch*4097 + 1 + t*16;
  #pragma unroll
  for (int i = 0; i < 16; i++) op[i] = pg[i]*inv;
}

extern "C" void kernel_launch(void* const* d_in, const int* in_sizes, int n_in,
                              void* d_out, int out_size, void* d_ws, size_t ws_size,
                              hipStream_t stream){
  const float* grd  = (const float*)d_in[0];
  const float* pts  = (const float*)d_in[1];
  const float* satl = (const float*)d_in[2];
  const float* gw1  = (const float*)d_in[3];
  const float* gb1  = (const float*)d_in[4];
  const float* gw2  = (const float*)d_in[5];
  const float* gb2  = (const float*)d_in[6];
  const float* sw1  = (const float*)d_in[7];
  const float* sb1  = (const float*)d_in[8];
  const float* sw2  = (const float*)d_in[9];
  const float* sb2  = (const float*)d_in[10];
  const float* pw1  = (const float*)d_in[11];
  const float* pb1  = (const float*)d_in[12];
  const float* pw2  = (const float*)d_in[13];
  const float* pb2  = (const float*)d_in[14];
  float* out = (float*)d_out;
  float* W = (float*)d_ws;
  float* mg   = W + 0;        // (128,256)
  float* msat = W + 32768;    // (128,256)
  float* mp   = W + 65536;    // (128,1024)
  float* mgrd = W + 196608;   // (128,128,8)
  float* wgrd = W + 327680;   // (128,256,8)
  float* mpc  = W + 589824;   // (128,512,8)
  float* wpc  = W + 1114112;  // (128,1024,8)
  float* gun  = W + 2162688;  // (128,4096)
  float* pun  = W + 2686976;  // (128,4096)
  float* ssg  = W + 3211264;  // (128)
  float* ssp  = W + 3211392;  // (128)

  hipMemsetAsync(ssg, 0, 256*sizeof(float), stream);
  k_masks<<<768, 256, 0, stream>>>(grd, pts, satl, mg, mp, msat);
  k_sa1<<<dim3(4, 16),  256, 0, stream>>>(mg, gw1, gb1, mgrd, 256, 1024);
  k_sa1<<<dim3(16, 16), 256, 0, stream>>>(mp, pw1, pb1, mpc, 1024, 4096);
  k_sa2<<<dim3(8, 16),  256, 0, stream>>>(mgrd, gw2, gb2, wgrd, 128, 2048, 1024);
  k_sa2<<<dim3(32, 16), 256, 0, stream>>>(mpc, pw2, pb2, wpc, 512, 8192, 4096);
  k_gemm<<<512, 256, 0, stream>>>(grd, wgrd, gun, ssg, 256);
  k_gemm<<<512, 256, 0, stream>>>(pts, wpc, pun, ssp, 1024);
  k_sat<<<8192, 256, 0, stream>>>(satl, msat, sw1, sb1, sw2, sb2,
                                  gun, pun, ssg, ssp, out);
}

// Round 11
// 843.178 us; speedup vs baseline: 1.6975x; 1.0158x over previous
//
#include <hip/hip_runtime.h>

#define DI __device__ __forceinline__

DI float4 fmax4(float4 a, float4 b){
  return make_float4(fmaxf(a.x,b.x),fmaxf(a.y,b.y),fmaxf(a.z,b.z),fmaxf(a.w,b.w));
}

DI float wred(float v){
  #pragma unroll
  for (int o = 32; o > 0; o >>= 1) v += __shfl_xor(v, o, 64);
  return v;
}

DI void facc(float4& a, float s, float4 w){
  a.x += s*w.x; a.y += s*w.y; a.z += s*w.z; a.w += s*w.w;
}

// ---------------------------------------------------------------------------
// Fused channel-max over (B,512,P) for grd (P=256), sat (P=256), pts (P=1024).
// ---------------------------------------------------------------------------
__global__ __launch_bounds__(256) void k_masks(const float* __restrict__ g,
    const float* __restrict__ p, const float* __restrict__ s,
    float* __restrict__ mg, float* __restrict__ mp, float* __restrict__ ms){
  __shared__ float4 lds[256];
  int t = threadIdx.x;
  int o = blockIdx.x * 64 + (t & 63);
  int ck = t >> 6;
  const float* src; float* dst; int b, p4, P4;
  if (o < 8192)       { b = o >> 6;            p4 = o & 63;          src = g; dst = mg; P4 = 64;  }
  else if (o < 16384) { int q = o - 8192;  b = q >> 6;  p4 = q & 63;  src = s; dst = ms; P4 = 64;  }
  else                { int q = o - 16384; b = q >> 8;  p4 = q & 255; src = p; dst = mp; P4 = 256; }
  const float4* a = (const float4*)src + ((size_t)b*512 + (size_t)ck*128) * P4 + p4;
  float4 v0 = make_float4(-1e30f,-1e30f,-1e30f,-1e30f), v1 = v0, v2 = v0, v3 = v0;
  for (int cc = 0; cc < 128; cc += 4){
    v0 = fmax4(v0, a[0]);
    v1 = fmax4(v1, a[(size_t)P4]);
    v2 = fmax4(v2, a[(size_t)2*P4]);
    v3 = fmax4(v3, a[(size_t)3*P4]);
    a += (size_t)4*P4;
  }
  v0 = fmax4(fmax4(v0,v1), fmax4(v2,v3));
  lds[t] = v0;
  __syncthreads();
  if (t < 64){
    float4 r = fmax4(fmax4(lds[t], lds[t+64]), fmax4(lds[t+128], lds[t+192]));
    ((float4*)dst)[(size_t)b*P4 + p4] = r;
  }
}

// ---------------------------------------------------------------------------
// SA stage 1: m[b,jd] = sum_i mask[b,i] * w1[i,jd] + b1[jd]
// ---------------------------------------------------------------------------
__global__ __launch_bounds__(256) void k_sa1(const float* __restrict__ mask,
    const float* __restrict__ w1, const float* __restrict__ b1,
    float* __restrict__ m, int I, int J8){
  __shared__ float4 red[2048];
  int t = threadIdx.x;
  int tx = t & 63, tg = t >> 6;
  int jd = blockIdx.x*256 + tx*4;
  int b0 = blockIdx.y*8;
  int KC = I >> 2;
  int k0 = tg*KC;
  float4 acc[8];
  #pragma unroll
  for (int u = 0; u < 8; u++) acc[u] = make_float4(0,0,0,0);
  const float* w1p = w1 + (size_t)k0*J8 + jd;
  for (int kk = 0; kk < KC; kk += 4){
    float mv[8][4];
    #pragma unroll
    for (int u = 0; u < 8; u++){
      float4 q = *(const float4*)(mask + (size_t)(b0+u)*I + k0 + kk);
      mv[u][0]=q.x; mv[u][1]=q.y; mv[u][2]=q.z; mv[u][3]=q.w;
    }
    #pragma unroll
    for (int s = 0; s < 4; s++){
      float4 w = *(const float4*)(w1p + (size_t)s*J8);
      #pragma unroll
      for (int u = 0; u < 8; u++) facc(acc[u], mv[u][s], w);
    }
    w1p += (size_t)4*J8;
  }
  #pragma unroll
  for (int u = 0; u < 8; u++) red[(tg*64+tx)*8 + (u ^ (tx&7))] = acc[u];
  __syncthreads();
  #pragma unroll
  for (int e = 0; e < 2; e++){
    int oi = t*2 + e;
    int ox = oi >> 3, ob = oi & 7;
    float4 s = make_float4(0,0,0,0);
    #pragma unroll
    for (int g = 0; g < 4; g++){
      float4 v = red[(g*64+ox)*8 + (ob ^ (ox&7))];
      s.x+=v.x; s.y+=v.y; s.z+=v.z; s.w+=v.w;
    }
    int jd2 = blockIdx.x*256 + ox*4;
    float4 bv = *(const float4*)(b1 + jd2);
    s.x+=bv.x; s.y+=bv.y; s.z+=bv.z; s.w+=bv.w;
    *(float4*)(m + (size_t)(b0+ob)*J8 + jd2) = s;
  }
}

// ---------------------------------------------------------------------------
// SA stage 2: w[b,id] = sum_j m[b,j*8+d] * w2[j,id] + b2[id]   (d = id&7)
// ---------------------------------------------------------------------------
__global__ __launch_bounds__(256) void k_sa2(const float* __restrict__ m,
    const float* __restrict__ w2, const float* __restrict__ b2,
    float* __restrict__ w, int J, int I8, int J8m){
  __shared__ float4 red[2048];
  int t = threadIdx.x;
  int tx = t & 63, tg = t >> 6;
  int id = blockIdx.x*256 + tx*4;
  int quad = id & 4;
  int b0 = blockIdx.y*8;
  int KC = J >> 2;
  int j0 = tg*KC;
  float4 acc[8];
  #pragma unroll
  for (int u = 0; u < 8; u++) acc[u] = make_float4(0,0,0,0);
  const float* w2p = w2 + (size_t)j0*I8 + id;
  for (int j = 0; j < KC; j++){
    float4 wv = *(const float4*)w2p; w2p += I8;
    #pragma unroll
    for (int u = 0; u < 8; u++){
      float4 mv = *(const float4*)(m + (size_t)(b0+u)*J8m + (size_t)(j0+j)*8 + quad);
      acc[u].x += mv.x*wv.x; acc[u].y += mv.y*wv.y;
      acc[u].z += mv.z*wv.z; acc[u].w += mv.w*wv.w;
    }
  }
  #pragma unroll
  for (int u = 0; u < 8; u++) red[(tg*64+tx)*8 + (u ^ (tx&7))] = acc[u];
  __syncthreads();
  #pragma unroll
  for (int e = 0; e < 2; e++){
    int oi = t*2 + e;
    int ox = oi >> 3, ob = oi & 7;
    float4 s = make_float4(0,0,0,0);
    #pragma unroll
    for (int g = 0; g < 4; g++){
      float4 v = red[(g*64+ox)*8 + (ob ^ (ox&7))];
      s.x+=v.x; s.y+=v.y; s.z+=v.z; s.w+=v.w;
    }
    int id2 = blockIdx.x*256 + ox*4;
    float4 bv = *(const float4*)(b2 + id2);
    s.x+=bv.x; s.y+=bv.y; s.z+=bv.z; s.w+=bv.w;
    *(float4*)(w + (size_t)(b0+ob)*I8 + id2) = s;
  }
}

// ---------------------------------------------------------------------------
// out[b,c,d] = sum_k A[b,c,k] * W[b,k,d]  (c in 512, d in 8), + sumsq per b.
// ---------------------------------------------------------------------------
__global__ __launch_bounds__(256) void k_gemm(const float* __restrict__ A,
    const float* __restrict__ W, float* __restrict__ out,
    float* __restrict__ ssq, int K){
  __shared__ float wl[8192];
  __shared__ float red[256*17];
  int t = threadIdx.x;
  int b = blockIdx.x >> 2, ct = blockIdx.x & 3;
  int K8 = K*8;
  for (int idx = t*4; idx < K8; idx += 1024)
    *(float4*)(wl + idx) = *(const float4*)(W + (size_t)b*K8 + idx);
  __syncthreads();
  int r = t & 63, kh = t >> 6;
  int Ks = K >> 2;
  const float* a0 = A + ((size_t)b*512 + ct*128 + r*2) * K + kh*Ks;
  float acc[16];
  #pragma unroll
  for (int i = 0; i < 16; i++) acc[i] = 0.f;
  for (int kk = 0; kk < Ks; kk += 4){
    float4 x0 = *(const float4*)(a0 + kk);
    float4 x1 = *(const float4*)(a0 + K + kk);
    const float* wp = wl + (kh*Ks + kk)*8;
    float xs0[4] = {x0.x, x0.y, x0.z, x0.w};
    float xs1[4] = {x1.x, x1.y, x1.z, x1.w};
    #pragma unroll
    for (int mm = 0; mm < 4; mm++){
      #pragma unroll
      for (int d = 0; d < 8; d++){
        float wv = wp[mm*8 + d];
        acc[d]     += xs0[mm]*wv;
        acc[8 + d] += xs1[mm]*wv;
      }
    }
  }
  float* rp = red + t*17;
  #pragma unroll
  for (int i = 0; i < 16; i++) rp[i] = acc[i];
  __syncthreads();
  if (t < 64){
    float v[16];
    #pragma unroll
    for (int i = 0; i < 16; i++)
      v[i] = red[t*17 + i] + red[(t+64)*17 + i] + red[(t+128)*17 + i] + red[(t+192)*17 + i];
    float* op = out + ((size_t)b*512 + ct*128 + t*2) * 8;
    #pragma unroll
    for (int i = 0; i < 16; i += 4)
      *(float4*)(op + i) = make_float4(v[i], v[i+1], v[i+2], v[i+3]);
    float s = 0.f;
    #pragma unroll
    for (int i = 0; i < 16; i++) s += v[i]*v[i];
    s = wred(s);
    if (t == 0) atomicAdd(ssq + b, s);
  }
}

// ---------------------------------------------------------------------------
// Per-patch (8192): sat SA inline, patch GEMM (512x4 @ 4x8), L2 norm,
// dots vs normalized grd/pts descriptors. Output row staged in LDS and
// written with alignment-fixed coalesced float4 stores (row stride 4097
// floats breaks natural 16B alignment; head h=(4-(patch&3))&3 scalars).
// ---------------------------------------------------------------------------
#define OUT2_OFF 33562624
__global__ __launch_bounds__(256) void k_sat(const float* __restrict__ sat,
    const float* __restrict__ msat,
    const float* __restrict__ w1, const float* __restrict__ b1,
    const float* __restrict__ w2, const float* __restrict__ b2,
    const float* __restrict__ gun, const float* __restrict__ pun,
    const float* __restrict__ ssg, const float* __restrict__ ssp,
    float* __restrict__ out){
  __shared__ float ml[16];
  __shared__ float wl[32];
  __shared__ float rl[4][3];
  __shared__ float bcast[1];
  __shared__ float row[4104];
  int t = threadIdx.x;
  int patch = blockIdx.x;
  int b = patch >> 6, s1 = (patch >> 3) & 7, s2 = patch & 7;
  int sbase = s1*32 + s2*2;
  if (t < 16){
    int j = t >> 3, d = t & 7;
    float acc = b1[j*8 + d];
    #pragma unroll
    for (int k = 0; k < 4; k++){
      float mk = msat[(size_t)b*256 + sbase + (k>>1)*16 + (k&1)];
      acc += mk * w1[k*16 + j*8 + d];
    }
    ml[t] = acc;
  }
  __syncthreads();
  if (t < 32){
    int i = t >> 3, d = t & 7;
    float acc = b2[i*8 + d];
    acc += ml[d]*w2[i*8 + d] + ml[8 + d]*w2[32 + i*8 + d];
    wl[t] = acc;
  }
  __syncthreads();
  float wr[4][8];
  #pragma unroll
  for (int k = 0; k < 4; k++)
    #pragma unroll
    for (int d = 0; d < 8; d++) wr[k][d] = wl[k*8 + d];
  const float* ap = sat + ((size_t)b*512 + 2*t) * 256 + sbase;
  float pg[16];
  #pragma unroll
  for (int cc = 0; cc < 2; cc++){
    const float* a = ap + cc*256;
    float2 lo = *(const float2*)(a);
    float2 hi = *(const float2*)(a + 16);
    #pragma unroll
    for (int d = 0; d < 8; d++)
      pg[cc*8 + d] = lo.x*wr[0][d] + lo.y*wr[1][d] + hi.x*wr[2][d] + hi.y*wr[3][d];
  }
  const float* g = gun + (size_t)b*4096 + t*16;
  const float* p = pun + (size_t)b*4096 + t*16;
  float ss = 0.f, dg = 0.f, dp = 0.f;
  #pragma unroll
  for (int i = 0; i < 16; i++){
    ss += pg[i]*pg[i];
    dg += pg[i]*g[i];
    dp += pg[i]*p[i];
  }
  ss = wred(ss); dg = wred(dg); dp = wred(dp);
  int wv = t >> 6;
  if ((t & 63) == 0){ rl[wv][0] = ss; rl[wv][1] = dg; rl[wv][2] = dp; }
  __syncthreads();
  if (t == 0){
    float sst = rl[0][0] + rl[1][0] + rl[2][0] + rl[3][0];
    float dgt = rl[0][1] + rl[1][1] + rl[2][1] + rl[3][1];
    float dpt = rl[0][2] + rl[1][2] + rl[2][2] + rl[3][2];
    float satn = fmaxf(sqrtf(sst), 1e-12f);
    float inv = 1.f / satn;
    float gn = fmaxf(sqrtf(ssg[b]), 1e-12f);
    float pn = fmaxf(sqrtf(ssp[b]), 1e-12f);
    float msv = dgt*inv/gn + dpt*inv/pn;
    bcast[0] = inv;
    row[0] = msv;
    out[OUT2_OFF + (size_t)patch] = msv;
  }
  __syncthreads();
  float inv = bcast[0];
  #pragma unroll
  for (int i = 0; i < 16; i++) row[1 + t*16 + i] = pg[i]*inv;
  __syncthreads();
  float* obase = out + (size_t)patch*4097;
  int h = (4 - (patch & 3)) & 3;           // scalars until 16B alignment
  if (t < h) obase[t] = row[t];
  int nf4 = (4097 - h) >> 2;
  for (int i = t; i < nf4; i += 256){
    int off = h + i*4;
    *(float4*)(obase + off) = make_float4(row[off], row[off+1], row[off+2], row[off+3]);
  }
  int done = h + nf4*4;
  int tail = 4097 - done;
  if (t < tail) obase[done + t] = row[done + t];
}

extern "C" void kernel_launch(void* const* d_in, const int* in_sizes, int n_in,
                              void* d_out, int out_size, void* d_ws, size_t ws_size,
                              hipStream_t stream){
  const float* grd  = (const float*)d_in[0];
  const float* pts  = (const float*)d_in[1];
  const float* satl = (const float*)d_in[2];
  const float* gw1  = (const float*)d_in[3];
  const float* gb1  = (const float*)d_in[4];
  const float* gw2  = (const float*)d_in[5];
  const float* gb2  = (const float*)d_in[6];
  const float* sw1  = (const float*)d_in[7];
  const float* sb1  = (const float*)d_in[8];
  const float* sw2  = (const float*)d_in[9];
  const float* sb2  = (const float*)d_in[10];
  const float* pw1  = (const float*)d_in[11];
  const float* pb1  = (const float*)d_in[12];
  const float* pw2  = (const float*)d_in[13];
  const float* pb2  = (const float*)d_in[14];
  float* out = (float*)d_out;
  float* W = (float*)d_ws;
  float* mg   = W + 0;        // (128,256)
  float* msat = W + 32768;    // (128,256)
  float* mp   = W + 65536;    // (128,1024)
  float* mgrd = W + 196608;   // (128,128,8)
  float* wgrd = W + 327680;   // (128,256,8)
  float* mpc  = W + 589824;   // (128,512,8)
  float* wpc  = W + 1114112;  // (128,1024,8)
  float* gun  = W + 2162688;  // (128,4096)
  float* pun  = W + 2686976;  // (128,4096)
  float* ssg  = W + 3211264;  // (128)
  float* ssp  = W + 3211392;  // (128)

  hipMemsetAsync(ssg, 0, 256*sizeof(float), stream);
  k_masks<<<768, 256, 0, stream>>>(grd, pts, satl, mg, mp, msat);
  k_sa1<<<dim3(4, 16),  256, 0, stream>>>(mg, gw1, gb1, mgrd, 256, 1024);
  k_sa1<<<dim3(16, 16), 256, 0, stream>>>(mp, pw1, pb1, mpc, 1024, 4096);
  k_sa2<<<dim3(8, 16),  256, 0, stream>>>(mgrd, gw2, gb2, wgrd, 128, 2048, 1024);
  k_sa2<<<dim3(32, 16), 256, 0, stream>>>(mpc, pw2, pb2, wpc, 512, 8192, 4096);
  k_gemm<<<512, 256, 0, stream>>>(grd, wgrd, gun, ssg, 256);
  k_gemm<<<512, 256, 0, stream>>>(pts, wpc, pun, ssp, 1024);
  k_sat<<<8192, 256, 0, stream>>>(satl, msat, sw1, sb1, sw2, sb2,
                                  gun, pun, ssg, ssp, out);
}